// Round 12
// baseline (300.719 us; speedup 1.0000x reference)
//
#include <hip/hip_runtime.h>
#include <hip/hip_bf16.h>

#define N_NODES 10000
#define N_EDGES 160000

typedef __hip_bfloat16 bf16;
typedef unsigned short u16;
typedef float f32x4 __attribute__((ext_vector_type(4)));
typedef short s16x8 __attribute__((ext_vector_type(8)));
typedef unsigned short us8 __attribute__((ext_vector_type(8)));
typedef unsigned short us4 __attribute__((ext_vector_type(4)));

static __device__ __forceinline__ float b2f(u16 u) {
    unsigned v = (unsigned)u << 16;
    return __uint_as_float(v);
}
static __device__ __forceinline__ u16 f2b(float f) {
    bf16 b = __float2bfloat16(f);
    return *reinterpret_cast<u16*>(&b);
}

// async global->LDS, 16B/lane; LDS dest = wave-uniform base + lane*16
#define GLDS(gp, lp)                                                         \
    __builtin_amdgcn_global_load_lds(                                        \
        (const __attribute__((address_space(1))) void*)(const void*)(gp),    \
        (__attribute__((address_space(3))) void*)(lp), 16, 0, 0)

template <int CE> struct VecSel;
template <> struct VecSel<4> { typedef us4 T; };
template <> struct VecSel<8> { typedef us8 T; };

// ---------------- prep ----------------

__global__ void k_prep0(const int* __restrict__ ei,
                        int* __restrict__ row, int* __restrict__ col,
                        int* __restrict__ deg) {
    bool is64 = true;
#pragma unroll
    for (int i = 0; i < 8; ++i) is64 = is64 && (ei[2 * i + 1] == 0);
    int t = blockIdx.x * 256 + threadIdx.x;
    if (t < N_NODES) deg[t] = 0;
    if (t < N_EDGES) {
        if (is64) {
            row[t] = ei[2 * t];
            col[t] = ei[2 * (N_EDGES + t)];
        } else {
            row[t] = ei[t];
            col[t] = ei[N_EDGES + t];
        }
    }
}

__global__ void k_count(const int* __restrict__ col, int* deg) {
    int e = blockIdx.x * 256 + threadIdx.x;
    if (e < N_EDGES) atomicAdd(&deg[col[e]], 1);
}

__global__ void k_scan_all(const int* __restrict__ deg, float* __restrict__ dis,
                           int* __restrict__ off, int* __restrict__ cur) {
    __shared__ int sums[256];
    int t = threadIdx.x;
    const int seg = (N_NODES + 255) >> 8;
    int lo = t * seg, hi = lo + seg;
    if (lo > N_NODES) lo = N_NODES;
    if (hi > N_NODES) hi = N_NODES;
    int s = 0;
    for (int i = lo; i < hi; ++i) {
        dis[i] = rsqrtf((float)deg[i] + 1.0f);
        s += deg[i];
    }
    sums[t] = s;
    __syncthreads();
    for (int d = 1; d < 256; d <<= 1) {
        int v = (t >= d) ? sums[t - d] : 0;
        __syncthreads();
        sums[t] += v;
        __syncthreads();
    }
    int run = sums[t] - s;
    for (int i = lo; i < hi; ++i) {
        off[i] = run;
        cur[i] = run;
        run += deg[i];
    }
    if (t == 255) off[N_NODES] = sums[255];
}

__global__ void k_fill(const int* __restrict__ row, const int* __restrict__ col,
                       const float* __restrict__ dis, int* cur,
                       int* __restrict__ crow, float* __restrict__ cnorm) {
    int e = blockIdx.x * 256 + threadIdx.x;
    if (e < N_EDGES) {
        int r = row[e], c = col[e];
        int p = atomicAdd(&cur[c], 1);
        crow[p] = r;
        cnorm[p] = dis[r] * dis[c];
    }
}

__global__ void k_convx(const float* __restrict__ x, u16* __restrict__ xb) {
    int i = blockIdx.x * 256 + threadIdx.x;
    float4 v = *(const float4*)(x + (size_t)i * 4);
    us4 st;
    st[0] = f2b(v.x); st[1] = f2b(v.y); st[2] = f2b(v.z); st[3] = f2b(v.w);
    *(us4*)(xb + (size_t)i * 4) = st;
}

__global__ void k_transpose(const float* __restrict__ W1, const float* __restrict__ W2,
                            const float* __restrict__ W3, const float* __restrict__ W4,
                            u16* __restrict__ T1, u16* __restrict__ T2,
                            u16* __restrict__ T3, u16* __restrict__ T4) {
    __shared__ u16 tile[32][33];
    int z = blockIdx.z;
    const float* W = (z == 0) ? W1 : (z == 1) ? W2 : (z == 2) ? W3 : W4;
    u16* WT        = (z == 0) ? T1 : (z == 1) ? T2 : (z == 2) ? T3 : T4;
    int K = (z == 0) ? 256 : 512;
    int k0 = blockIdx.y * 32;
    if (k0 >= K) return;
    int n0 = blockIdx.x * 32;
    int tx = threadIdx.x, ty = threadIdx.y;
    for (int i = 0; i < 32; i += 8)
        tile[ty + i][tx] = f2b(W[(size_t)(k0 + ty + i) * 512 + n0 + tx]);
    __syncthreads();
    for (int i = 0; i < 32; i += 8)
        WT[(size_t)(n0 + ty + i) * K + k0 + tx] = tile[tx][ty + i];
}

// ---------------- CSR-gather aggregation, bf16 in/out, f32 accumulate -------------
// NCH waves per node, CE = C/(64*NCH) elems/lane. 4-way unrolled edge loop
// (4 independent accumulate chains -> 4 outstanding gathers). Self-loop fused.

template <int C, int NCH>
__global__ void k_agg(const u16* __restrict__ in, u16* __restrict__ out,
                      const int* __restrict__ off, const int* __restrict__ crow,
                      const float* __restrict__ cnorm, const float* __restrict__ dis) {
    const int CE = C / (64 * NCH);
    typedef typename VecSel<CE>::T VT;
    int wid = blockIdx.x * 4 + (threadIdx.x >> 6);
    int lane = threadIdx.x & 63;
    int node = wid / NCH;
    if (node >= N_NODES) return;
    int ch = wid % NCH;
    int c = ch * (CE * 64) + lane * CE;

    float d = dis[node];
    VT sv = *(const VT*)(in + (size_t)node * C + c);
    float a0[CE], a1[CE], a2[CE], a3[CE];
#pragma unroll
    for (int j = 0; j < CE; ++j) {
        a0[j] = b2f(sv[j]) * d * d;
        a1[j] = 0.f; a2[j] = 0.f; a3[j] = 0.f;
    }

    int b = off[node], e = off[node + 1];
    int i = b;
    for (; i + 3 < e; i += 4) {
        int r0 = crow[i], r1 = crow[i + 1], r2 = crow[i + 2], r3 = crow[i + 3];
        float n0 = cnorm[i], n1 = cnorm[i + 1], n2 = cnorm[i + 2], n3 = cnorm[i + 3];
        VT v0 = *(const VT*)(in + (size_t)r0 * C + c);
        VT v1 = *(const VT*)(in + (size_t)r1 * C + c);
        VT v2 = *(const VT*)(in + (size_t)r2 * C + c);
        VT v3 = *(const VT*)(in + (size_t)r3 * C + c);
#pragma unroll
        for (int j = 0; j < CE; ++j) {
            a0[j] = fmaf(b2f(v0[j]), n0, a0[j]);
            a1[j] = fmaf(b2f(v1[j]), n1, a1[j]);
            a2[j] = fmaf(b2f(v2[j]), n2, a2[j]);
            a3[j] = fmaf(b2f(v3[j]), n3, a3[j]);
        }
    }
    for (; i < e; ++i) {
        int r0 = crow[i];
        float n0 = cnorm[i];
        VT v0 = *(const VT*)(in + (size_t)r0 * C + c);
#pragma unroll
        for (int j = 0; j < CE; ++j) a0[j] = fmaf(b2f(v0[j]), n0, a0[j]);
    }
    VT st;
#pragma unroll
    for (int j = 0; j < CE; ++j) st[j] = f2b((a0[j] + a1[j]) + (a2[j] + a3[j]));
    *(VT*)(out + (size_t)node * C + c) = st;
}

// ---------------- LDS-staged bf16 MFMA GEMM, BK=128 (4 x 32-k panels) -------------
// 64x64 tile, 4 waves 2x2, wave 32x32. Wave w stages panel w of A and B
// (4+4 GLDS width-16). 2 barriers per 128-k. 64B LDS rows: 2-way aliasing free.
// A rows clamped to M-1 (feed only store-guarded output rows).

static __device__ __forceinline__ void st_out(float* out, size_t idx, float v) { out[idx] = v; }
static __device__ __forceinline__ void st_out(u16* out, size_t idx, float v) { out[idx] = f2b(v); }

template <typename OT>
__global__ __launch_bounds__(256) void k_gemm(
        const u16* __restrict__ A, const u16* __restrict__ BT,
        const float* __restrict__ bias, OT* __restrict__ out,
        int M, int K, int NO, int relu) {
    __shared__ u16 As[4][64][32];
    __shared__ u16 Bs[4][64][32];

    int tid = threadIdx.x;
    int w = tid >> 6;
    int lane = tid & 63;
    int wm = w >> 1, wn = w & 1;
    int m0 = blockIdx.x * 64;
    int n0 = blockIdx.y * 64;
    int l15 = lane & 15;
    int kq = lane >> 4;

    int srow = lane >> 2;
    int skc  = (lane & 3) * 8;
    const u16* agp[4];
    const u16* bgp[4];
    u16* al[4];
    u16* bl[4];
#pragma unroll
    for (int j = 0; j < 4; ++j) {
        int arw = m0 + j * 16 + srow; if (arw > M - 1) arw = M - 1;
        agp[j] = A + (size_t)arw * K + w * 32 + skc;
        bgp[j] = BT + (size_t)(n0 + j * 16 + srow) * K + w * 32 + skc;
        al[j] = &As[w][j * 16][0];
        bl[j] = &Bs[w][j * 16][0];
    }

    int aRow0 = wm * 32 + l15, aRow1 = aRow0 + 16;
    int bRow0 = wn * 32 + l15, bRow1 = bRow0 + 16;

    f32x4 acc00 = {0.f, 0.f, 0.f, 0.f};
    f32x4 acc01 = acc00, acc10 = acc00, acc11 = acc00;

    for (int k0 = 0; k0 < K; k0 += 128) {
#pragma unroll
        for (int j = 0; j < 4; ++j) GLDS(agp[j] + k0, al[j]);
#pragma unroll
        for (int j = 0; j < 4; ++j) GLDS(bgp[j] + k0, bl[j]);
        __syncthreads();
#pragma unroll
        for (int p = 0; p < 4; ++p) {
            s16x8 a0 = *(const s16x8*)&As[p][aRow0][kq * 8];
            s16x8 a1 = *(const s16x8*)&As[p][aRow1][kq * 8];
            s16x8 b0 = *(const s16x8*)&Bs[p][bRow0][kq * 8];
            s16x8 b1 = *(const s16x8*)&Bs[p][bRow1][kq * 8];
            acc00 = __builtin_amdgcn_mfma_f32_16x16x32_bf16(a0, b0, acc00, 0, 0, 0);
            acc01 = __builtin_amdgcn_mfma_f32_16x16x32_bf16(a0, b1, acc01, 0, 0, 0);
            acc10 = __builtin_amdgcn_mfma_f32_16x16x32_bf16(a1, b0, acc10, 0, 0, 0);
            acc11 = __builtin_amdgcn_mfma_f32_16x16x32_bf16(a1, b1, acc11, 0, 0, 0);
        }
        __syncthreads();
    }

    // C/D layout: col = lane&15, row = (lane>>4)*4 + r   [m89-verified]
    int r0 = (lane >> 4) * 4;
    int cm0 = m0 + wm * 32;
    int cn0 = n0 + wn * 32;
    float bv0 = bias[cn0 + l15];
    float bv1 = bias[cn0 + 16 + l15];
#pragma unroll
    for (int r = 0; r < 4; ++r) {
        int rowa = cm0 + r0 + r;
        if (rowa < M) {
            float v = acc00[r] + bv0;
            if (relu) v = fmaxf(v, 0.f);
            st_out(out, (size_t)rowa * NO + cn0 + l15, v);
            v = acc01[r] + bv1;
            if (relu) v = fmaxf(v, 0.f);
            st_out(out, (size_t)rowa * NO + cn0 + 16 + l15, v);
        }
        int rowb = rowa + 16;
        if (rowb < M) {
            float v = acc10[r] + bv0;
            if (relu) v = fmaxf(v, 0.f);
            st_out(out, (size_t)rowb * NO + cn0 + l15, v);
            v = acc11[r] + bv1;
            if (relu) v = fmaxf(v, 0.f);
            st_out(out, (size_t)rowb * NO + cn0 + 16 + l15, v);
        }
    }
}

// ---------------- launch ----------------

extern "C" void kernel_launch(void* const* d_in, const int* in_sizes, int n_in,
                              void* d_out, int out_size, void* d_ws, size_t ws_size,
                              hipStream_t stream) {
    const float* x  = (const float*)d_in[0];
    const int*   ei = (const int*)d_in[1];
    const float* W1 = (const float*)d_in[2];
    const float* b1 = (const float*)d_in[3];
    const float* W2 = (const float*)d_in[4];
    const float* b2 = (const float*)d_in[5];
    const float* W3 = (const float*)d_in[6];
    const float* b3 = (const float*)d_in[7];
    const float* W4 = (const float*)d_in[8];
    const float* b4 = (const float*)d_in[9];

    char* ws = (char*)d_ws;
    size_t o = 0;
    auto alloc = [&](size_t bytes) {
        char* p = ws + o;
        o = (o + bytes + 255) & ~(size_t)255;
        return p;
    };
    int*   row   = (int*)alloc(N_EDGES * 4);
    int*   col   = (int*)alloc(N_EDGES * 4);
    int*   deg   = (int*)alloc(N_NODES * 4);
    float* dis   = (float*)alloc(N_NODES * 4);
    int*   off   = (int*)alloc((N_NODES + 1) * 4);
    int*   cur   = (int*)alloc(N_NODES * 4);
    int*   crow  = (int*)alloc(N_EDGES * 4);
    float* cnorm = (float*)alloc(N_EDGES * 4);
    u16*   WT1   = (u16*)alloc((size_t)512 * 256 * 2);
    u16*   WT2   = (u16*)alloc((size_t)512 * 512 * 2);
    u16*   WT3   = (u16*)alloc((size_t)512 * 512 * 2);
    u16*   WT4   = (u16*)alloc((size_t)512 * 512 * 2);
    u16*   xb    = (u16*)alloc((size_t)N_NODES * 256 * 2);
    u16*   s     = (u16*)alloc((size_t)N_NODES * 512 * 2);
    u16*   h     = (u16*)alloc((size_t)N_NODES * 512 * 2);
    float* outb  = (float*)d_out;

    dim3 b256(256);
    const int gE = (N_EDGES + 255) / 256;
    const dim3 gG(157, 8);
    const int gA1 = (N_NODES + 3) / 4;
    const int gA2 = (N_NODES * 2 + 3) / 4;

    k_prep0<<<gE, b256, 0, stream>>>(ei, row, col, deg);
    k_count<<<gE, b256, 0, stream>>>(col, deg);
    k_scan_all<<<1, b256, 0, stream>>>(deg, dis, off, cur);
    k_fill<<<gE, b256, 0, stream>>>(row, col, dis, cur, crow, cnorm);
    k_convx<<<N_NODES * 256 / 4 / 256, b256, 0, stream>>>(x, xb);
    k_transpose<<<dim3(16, 16, 4), dim3(32, 8), 0, stream>>>(W1, W2, W3, W4,
                                                             WT1, WT2, WT3, WT4);

    // Layer 1: s = bf16(A_norm @ x) [C=256], h = bf16(relu(s @ W1 + b1))
    k_agg<256, 1><<<gA1, b256, 0, stream>>>(xb, s, off, crow, cnorm, dis);
    k_gemm<u16><<<gG, b256, 0, stream>>>(s, WT1, b1, h, N_NODES, 256, 512, 1);
    // Layer 2
    k_agg<512, 2><<<gA2, b256, 0, stream>>>(h, s, off, crow, cnorm, dis);
    k_gemm<u16><<<gG, b256, 0, stream>>>(s, WT2, b2, h, N_NODES, 512, 512, 1);
    // Layer 3
    k_agg<512, 2><<<gA2, b256, 0, stream>>>(h, s, off, crow, cnorm, dis);
    k_gemm<u16><<<gG, b256, 0, stream>>>(s, WT3, b3, h, N_NODES, 512, 512, 1);
    // Layer 4 (no relu) -> f32 d_out
    k_agg<512, 2><<<gA2, b256, 0, stream>>>(h, s, off, crow, cnorm, dis);
    k_gemm<float><<<gG, b256, 0, stream>>>(s, WT4, b4, outb, N_NODES, 512, 512, 0);
}

// Round 13
// 296.499 us; speedup vs baseline: 1.0142x; 1.0142x over previous
//
#include <hip/hip_runtime.h>
#include <hip/hip_bf16.h>

#define N_NODES 10000
#define N_EDGES 160000

typedef __hip_bfloat16 bf16;
typedef unsigned short u16;
typedef float f32x4 __attribute__((ext_vector_type(4)));
typedef short s16x8 __attribute__((ext_vector_type(8)));
typedef unsigned short us8 __attribute__((ext_vector_type(8)));
typedef unsigned short us4 __attribute__((ext_vector_type(4)));

static __device__ __forceinline__ float b2f(u16 u) {
    unsigned v = (unsigned)u << 16;
    return __uint_as_float(v);
}
static __device__ __forceinline__ u16 f2b(float f) {
    bf16 b = __float2bfloat16(f);
    return *reinterpret_cast<u16*>(&b);
}

// async global->LDS, 16B/lane; LDS dest = wave-uniform base + lane*16
#define GLDS(gp, lp)                                                         \
    __builtin_amdgcn_global_load_lds(                                        \
        (const __attribute__((address_space(1))) void*)(const void*)(gp),    \
        (__attribute__((address_space(3))) void*)(lp), 16, 0, 0)

template <int CE> struct VecSel;
template <> struct VecSel<4> { typedef us4 T; };
template <> struct VecSel<8> { typedef us8 T; };

// ---------------- prep0: zero deg + extract edges + convert x to bf16 -------------

__global__ void k_prep0(const int* __restrict__ ei,
                        int* __restrict__ row, int* __restrict__ col,
                        int* __restrict__ deg,
                        const float* __restrict__ x, u16* __restrict__ xb) {
    bool is64 = true;
#pragma unroll
    for (int i = 0; i < 8; ++i) is64 = is64 && (ei[2 * i + 1] == 0);
    int t = blockIdx.x * 256 + threadIdx.x;
    if (t < N_NODES) deg[t] = 0;
    if (t < N_EDGES) {
        if (is64) {
            row[t] = ei[2 * t];
            col[t] = ei[2 * (N_EDGES + t)];
        } else {
            row[t] = ei[t];
            col[t] = ei[N_EDGES + t];
        }
    }
    // x conversion: t covers N_NODES*256/4 = 640000 float4 groups
    if (t < N_NODES * 256 / 4) {
        float4 v = *(const float4*)(x + (size_t)t * 4);
        us4 st;
        st[0] = f2b(v.x); st[1] = f2b(v.y); st[2] = f2b(v.z); st[3] = f2b(v.w);
        *(us4*)(xb + (size_t)t * 4) = st;
    }
}

__global__ void k_count(const int* __restrict__ col, int* deg) {
    int e = blockIdx.x * 256 + threadIdx.x;
    if (e < N_EDGES) atomicAdd(&deg[col[e]], 1);
}

__global__ void k_scan_all(const int* __restrict__ deg, float* __restrict__ dis,
                           int* __restrict__ off, int* __restrict__ cur) {
    __shared__ int sums[256];
    int t = threadIdx.x;
    const int seg = (N_NODES + 255) >> 8;
    int lo = t * seg, hi = lo + seg;
    if (lo > N_NODES) lo = N_NODES;
    if (hi > N_NODES) hi = N_NODES;
    int s = 0;
    for (int i = lo; i < hi; ++i) {
        dis[i] = rsqrtf((float)deg[i] + 1.0f);
        s += deg[i];
    }
    sums[t] = s;
    __syncthreads();
    for (int d = 1; d < 256; d <<= 1) {
        int v = (t >= d) ? sums[t - d] : 0;
        __syncthreads();
        sums[t] += v;
        __syncthreads();
    }
    int run = sums[t] - s;
    for (int i = lo; i < hi; ++i) {
        off[i] = run;
        cur[i] = run;
        run += deg[i];
    }
    if (t == 255) off[N_NODES] = sums[255];
}

__global__ void k_fill(const int* __restrict__ row, const int* __restrict__ col,
                       const float* __restrict__ dis, int* cur,
                       int* __restrict__ crow, float* __restrict__ cnorm) {
    int e = blockIdx.x * 256 + threadIdx.x;
    if (e < N_EDGES) {
        int r = row[e], c = col[e];
        int p = atomicAdd(&cur[c], 1);
        crow[p] = r;
        cnorm[p] = dis[r] * dis[c];
    }
}

__global__ void k_transpose(const float* __restrict__ W1, const float* __restrict__ W2,
                            const float* __restrict__ W3, const float* __restrict__ W4,
                            u16* __restrict__ T1, u16* __restrict__ T2,
                            u16* __restrict__ T3, u16* __restrict__ T4) {
    __shared__ u16 tile[32][33];
    int z = blockIdx.z;
    const float* W = (z == 0) ? W1 : (z == 1) ? W2 : (z == 2) ? W3 : W4;
    u16* WT        = (z == 0) ? T1 : (z == 1) ? T2 : (z == 2) ? T3 : T4;
    int K = (z == 0) ? 256 : 512;
    int k0 = blockIdx.y * 32;
    if (k0 >= K) return;
    int n0 = blockIdx.x * 32;
    int tx = threadIdx.x, ty = threadIdx.y;
    for (int i = 0; i < 32; i += 8)
        tile[ty + i][tx] = f2b(W[(size_t)(k0 + ty + i) * 512 + n0 + tx]);
    __syncthreads();
    for (int i = 0; i < 32; i += 8)
        WT[(size_t)(n0 + ty + i) * K + k0 + tx] = tile[tx][ty + i];
}

// ---------------- CSR-gather aggregation, bf16 in/out, f32 accumulate -------------
// One wave per node, CE = C/64 elems/lane (16B loads at C=512). 4-way unrolled
// edge loop (4 independent chains -> 4 outstanding gathers). Self-loop fused.

template <int C>
__global__ void k_agg(const u16* __restrict__ in, u16* __restrict__ out,
                      const int* __restrict__ off, const int* __restrict__ crow,
                      const float* __restrict__ cnorm, const float* __restrict__ dis) {
    const int CE = C / 64;
    typedef typename VecSel<CE>::T VT;
    int node = blockIdx.x * 4 + (threadIdx.x >> 6);
    int lane = threadIdx.x & 63;
    if (node >= N_NODES) return;
    int c = lane * CE;

    float d = dis[node];
    VT sv = *(const VT*)(in + (size_t)node * C + c);
    float a0[CE], a1[CE], a2[CE], a3[CE];
#pragma unroll
    for (int j = 0; j < CE; ++j) {
        a0[j] = b2f(sv[j]) * d * d;
        a1[j] = 0.f; a2[j] = 0.f; a3[j] = 0.f;
    }

    int b = off[node], e = off[node + 1];
    int i = b;
    for (; i + 3 < e; i += 4) {
        int r0 = crow[i], r1 = crow[i + 1], r2 = crow[i + 2], r3 = crow[i + 3];
        float n0 = cnorm[i], n1 = cnorm[i + 1], n2 = cnorm[i + 2], n3 = cnorm[i + 3];
        VT v0 = *(const VT*)(in + (size_t)r0 * C + c);
        VT v1 = *(const VT*)(in + (size_t)r1 * C + c);
        VT v2 = *(const VT*)(in + (size_t)r2 * C + c);
        VT v3 = *(const VT*)(in + (size_t)r3 * C + c);
#pragma unroll
        for (int j = 0; j < CE; ++j) {
            a0[j] = fmaf(b2f(v0[j]), n0, a0[j]);
            a1[j] = fmaf(b2f(v1[j]), n1, a1[j]);
            a2[j] = fmaf(b2f(v2[j]), n2, a2[j]);
            a3[j] = fmaf(b2f(v3[j]), n3, a3[j]);
        }
    }
    for (; i < e; ++i) {
        int r0 = crow[i];
        float n0 = cnorm[i];
        VT v0 = *(const VT*)(in + (size_t)r0 * C + c);
#pragma unroll
        for (int j = 0; j < CE; ++j) a0[j] = fmaf(b2f(v0[j]), n0, a0[j]);
    }
    VT st;
#pragma unroll
    for (int j = 0; j < CE; ++j) st[j] = f2b((a0[j] + a1[j]) + (a2[j] + a3[j]));
    *(VT*)(out + (size_t)node * C + c) = st;
}

// ---------------- LDS-staged bf16 MFMA GEMM, BK=64, double-buffered prefetch ------
// 64x64 tile, 4 waves 2x2, wave 32x32. ONE barrier per iter: GLDS for iter k+1
// issued right after the barrier into buf nb, consumed at the NEXT barrier —
// staging latency overlaps the whole MFMA phase (vs the 2-barrier drain).
// 64B LDS rows: uniform 8-access/bank b128 pattern = LDS floor, no conflicts.
// A rows clamped to M-1 (feed only store-guarded output rows).

static __device__ __forceinline__ void st_out(float* out, size_t idx, float v) { out[idx] = v; }
static __device__ __forceinline__ void st_out(u16* out, size_t idx, float v) { out[idx] = f2b(v); }

template <typename OT>
__global__ __launch_bounds__(256) void k_gemm(
        const u16* __restrict__ A, const u16* __restrict__ BT,
        const float* __restrict__ bias, OT* __restrict__ out,
        int M, int K, int NO, int relu) {
    __shared__ u16 As[2][2][64][32];  // [buf][panel][m][k]
    __shared__ u16 Bs[2][2][64][32];  // [buf][panel][n][k]

    int tid = threadIdx.x;
    int w = tid >> 6;
    int lane = tid & 63;
    int wm = w >> 1, wn = w & 1;
    int m0 = blockIdx.x * 64;
    int n0 = blockIdx.y * 64;
    int l15 = lane & 15;
    int kq = lane >> 4;

    // staging: wave w stages panel sp=(w&1), rows srb=(w>>1)*32 + {0,16}
    int sp  = w & 1;
    int srb = (w >> 1) * 32;
    int srow = lane >> 2;
    int skc  = (lane & 3) * 8;

    int ar0 = m0 + srb + srow;      if (ar0 > M - 1) ar0 = M - 1;
    int ar1 = m0 + srb + 16 + srow; if (ar1 > M - 1) ar1 = M - 1;
    const u16* agp0 = A + (size_t)ar0 * K + sp * 32 + skc;
    const u16* agp1 = A + (size_t)ar1 * K + sp * 32 + skc;
    const u16* bgp0 = BT + (size_t)(n0 + srb + srow) * K + sp * 32 + skc;
    const u16* bgp1 = BT + (size_t)(n0 + srb + 16 + srow) * K + sp * 32 + skc;

    int aRow0 = wm * 32 + l15, aRow1 = aRow0 + 16;
    int bRow0 = wn * 32 + l15, bRow1 = bRow0 + 16;

    f32x4 acc00 = {0.f, 0.f, 0.f, 0.f};
    f32x4 acc01 = acc00, acc10 = acc00, acc11 = acc00;

    // prologue: stage k=0 into buf 0
    GLDS(agp0, &As[0][sp][srb][0]);
    GLDS(agp1, &As[0][sp][srb + 16][0]);
    GLDS(bgp0, &Bs[0][sp][srb][0]);
    GLDS(bgp1, &Bs[0][sp][srb + 16][0]);

    int nIter = K >> 6;
    for (int it = 0; it < nIter; ++it) {
        __syncthreads();  // drains buf[cb] staging; protects buf[nb] overwrite
        int cb = it & 1, nb = cb ^ 1;
        if (it + 1 < nIter) {
            int kn = (it + 1) << 6;
            GLDS(agp0 + kn, &As[nb][sp][srb][0]);
            GLDS(agp1 + kn, &As[nb][sp][srb + 16][0]);
            GLDS(bgp0 + kn, &Bs[nb][sp][srb][0]);
            GLDS(bgp1 + kn, &Bs[nb][sp][srb + 16][0]);
        }
#pragma unroll
        for (int p = 0; p < 2; ++p) {
            s16x8 a0 = *(const s16x8*)&As[cb][p][aRow0][kq * 8];
            s16x8 a1 = *(const s16x8*)&As[cb][p][aRow1][kq * 8];
            s16x8 b0 = *(const s16x8*)&Bs[cb][p][bRow0][kq * 8];
            s16x8 b1 = *(const s16x8*)&Bs[cb][p][bRow1][kq * 8];
            acc00 = __builtin_amdgcn_mfma_f32_16x16x32_bf16(a0, b0, acc00, 0, 0, 0);
            acc01 = __builtin_amdgcn_mfma_f32_16x16x32_bf16(a0, b1, acc01, 0, 0, 0);
            acc10 = __builtin_amdgcn_mfma_f32_16x16x32_bf16(a1, b0, acc10, 0, 0, 0);
            acc11 = __builtin_amdgcn_mfma_f32_16x16x32_bf16(a1, b1, acc11, 0, 0, 0);
        }
    }

    // C/D layout: col = lane&15, row = (lane>>4)*4 + r   [m89-verified]
    int r0 = (lane >> 4) * 4;
    int cm0 = m0 + wm * 32;
    int cn0 = n0 + wn * 32;
    float bv0 = bias[cn0 + l15];
    float bv1 = bias[cn0 + 16 + l15];
#pragma unroll
    for (int r = 0; r < 4; ++r) {
        int rowa = cm0 + r0 + r;
        if (rowa < M) {
            float v = acc00[r] + bv0;
            if (relu) v = fmaxf(v, 0.f);
            st_out(out, (size_t)rowa * NO + cn0 + l15, v);
            v = acc01[r] + bv1;
            if (relu) v = fmaxf(v, 0.f);
            st_out(out, (size_t)rowa * NO + cn0 + 16 + l15, v);
        }
        int rowb = rowa + 16;
        if (rowb < M) {
            float v = acc10[r] + bv0;
            if (relu) v = fmaxf(v, 0.f);
            st_out(out, (size_t)rowb * NO + cn0 + l15, v);
            v = acc11[r] + bv1;
            if (relu) v = fmaxf(v, 0.f);
            st_out(out, (size_t)rowb * NO + cn0 + 16 + l15, v);
        }
    }
}

// ---------------- launch ----------------

extern "C" void kernel_launch(void* const* d_in, const int* in_sizes, int n_in,
                              void* d_out, int out_size, void* d_ws, size_t ws_size,
                              hipStream_t stream) {
    const float* x  = (const float*)d_in[0];
    const int*   ei = (const int*)d_in[1];
    const float* W1 = (const float*)d_in[2];
    const float* b1 = (const float*)d_in[3];
    const float* W2 = (const float*)d_in[4];
    const float* b2 = (const float*)d_in[5];
    const float* W3 = (const float*)d_in[6];
    const float* b3 = (const float*)d_in[7];
    const float* W4 = (const float*)d_in[8];
    const float* b4 = (const float*)d_in[9];

    char* ws = (char*)d_ws;
    size_t o = 0;
    auto alloc = [&](size_t bytes) {
        char* p = ws + o;
        o = (o + bytes + 255) & ~(size_t)255;
        return p;
    };
    int*   row   = (int*)alloc(N_EDGES * 4);
    int*   col   = (int*)alloc(N_EDGES * 4);
    int*   deg   = (int*)alloc(N_NODES * 4);
    float* dis   = (float*)alloc(N_NODES * 4);
    int*   off   = (int*)alloc((N_NODES + 1) * 4);
    int*   cur   = (int*)alloc(N_NODES * 4);
    int*   crow  = (int*)alloc(N_EDGES * 4);
    float* cnorm = (float*)alloc(N_EDGES * 4);
    u16*   WT1   = (u16*)alloc((size_t)512 * 256 * 2);
    u16*   WT2   = (u16*)alloc((size_t)512 * 512 * 2);
    u16*   WT3   = (u16*)alloc((size_t)512 * 512 * 2);
    u16*   WT4   = (u16*)alloc((size_t)512 * 512 * 2);
    u16*   xb    = (u16*)alloc((size_t)N_NODES * 256 * 2);
    u16*   s     = (u16*)alloc((size_t)N_NODES * 512 * 2);
    u16*   h     = (u16*)alloc((size_t)N_NODES * 512 * 2);
    float* outb  = (float*)d_out;

    dim3 b256(256);
    const int gE = (N_EDGES + 255) / 256;
    const int gP = (N_NODES * 256 / 4 + 255) / 256;  // 2500: covers edges+deg+convx
    const dim3 gG(157, 8);
    const int gA = (N_NODES + 3) / 4;

    k_prep0<<<gP, b256, 0, stream>>>(ei, row, col, deg, x, xb);
    k_count<<<gE, b256, 0, stream>>>(col, deg);
    k_scan_all<<<1, b256, 0, stream>>>(deg, dis, off, cur);
    k_fill<<<gE, b256, 0, stream>>>(row, col, dis, cur, crow, cnorm);
    k_transpose<<<dim3(16, 16, 4), dim3(32, 8), 0, stream>>>(W1, W2, W3, W4,
                                                             WT1, WT2, WT3, WT4);

    // Layer 1: s = bf16(A_norm @ x) [C=256], h = bf16(relu(s @ W1 + b1))
    k_agg<256><<<gA, b256, 0, stream>>>(xb, s, off, crow, cnorm, dis);
    k_gemm<u16><<<gG, b256, 0, stream>>>(s, WT1, b1, h, N_NODES, 256, 512, 1);
    // Layer 2
    k_agg<512><<<gA, b256, 0, stream>>>(h, s, off, crow, cnorm, dis);
    k_gemm<u16><<<gG, b256, 0, stream>>>(s, WT2, b2, h, N_NODES, 512, 512, 1);
    // Layer 3
    k_agg<512><<<gA, b256, 0, stream>>>(h, s, off, crow, cnorm, dis);
    k_gemm<u16><<<gG, b256, 0, stream>>>(s, WT3, b3, h, N_NODES, 512, 512, 1);
    // Layer 4 (no relu) -> f32 d_out
    k_agg<512><<<gA, b256, 0, stream>>>(h, s, off, crow, cnorm, dis);
    k_gemm<float><<<gG, b256, 0, stream>>>(s, WT4, b4, outb, N_NODES, 512, 512, 0);
}